// Round 8
// baseline (14211.104 us; speedup 1.0000x reference)
//
#include <hip/hip_runtime.h>
#include <hip/hip_bf16.h>
#include <stdint.h>

#define SEQ    200
#define BATCH  128
#define NHID   1024
#define NDEPTH 5
#define NBLK   256            // persistent blocks == CUs
#define CPB    4              // hidden columns owned per block
#define WSTRIDE (NHID + 16)   // LDS row stride (bf16): breaks power-of-2 bank aliasing
#define NGO    32             // replicated go lines
#define PANEL  ((size_t)BATCH * NHID)   // state panel elements

typedef __bf16 bf16x8 __attribute__((ext_vector_type(8)));
typedef float  f32x4  __attribute__((ext_vector_type(4)));
typedef uint32_t u32x4 __attribute__((ext_vector_type(4)));
typedef __hip_bfloat16 bf16_t;

__device__ __forceinline__ f32x4 mfma16(bf16x8 a, bf16x8 b, f32x4 c) {
    return __builtin_amdgcn_mfma_f32_16x16x32_bf16(a, b, c, 0, 0, 0);
}
__device__ __forceinline__ bf16x8 as_bf16x8(u32x4 x) {
    union { u32x4 u; bf16x8 b; } t; t.u = x; return t.b;
}
__device__ __forceinline__ unsigned short f32_to_bf16_bits(float f) {
    uint32_t x = __float_as_uint(f);
    uint32_t r = ((x >> 16) & 1u) + 0x7fffu;   // RNE
    return (unsigned short)((x + r) >> 16);
}
__device__ __forceinline__ int get_xcc_id() {
    int x;
    asm volatile("s_getreg_b32 %0, hwreg(HW_REG_XCC_ID)" : "=s"(x));
    return x & 7;
}

__global__ void k_prep_xm(const float* __restrict__ inp, const float* __restrict__ h_mask,
                          bf16_t* __restrict__ xm, int n) {
    for (int i = blockIdx.x * blockDim.x + threadIdx.x; i < n; i += gridDim.x * blockDim.x) {
        int r = i & (BATCH * NHID - 1);
        xm[i] = __float2bfloat16(inp[i] * h_mask[r]);
    }
}

__global__ void k_init_smb(const float* __restrict__ hidden, const float* __restrict__ s_mask,
                           bf16_t* __restrict__ smb, int n) {
    for (int i = blockIdx.x * blockDim.x + threadIdx.x; i < n; i += gridDim.x * blockDim.x)
        smb[i] = __float2bfloat16(hidden[i] * s_mask[i]);
}

// A loads: sc0 (L1-bypass, local-L2-served mirror) for state, plain cached for xm
#define LDU(i, OFF) asm volatile("global_load_dwordx4 %0, %1, off offset:" OFF " sc0" \
                                 : "=v"(AR[i]) : "v"(aptr));
#define LDCQ(i, OFF) asm volatile("global_load_dwordx4 %0, %1, off offset:" OFF \
                                 : "=v"(AR[i]) : "v"(xptr));
#define ISSUE32(M) \
    M(0,"0")    M(1,"64")   M(2,"128")  M(3,"192")  M(4,"256")  M(5,"320")  M(6,"384")  M(7,"448") \
    M(8,"512")  M(9,"576")  M(10,"640") M(11,"704") M(12,"768") M(13,"832") M(14,"896") M(15,"960") \
    M(16,"1024") M(17,"1088") M(18,"1152") M(19,"1216") M(20,"1280") M(21,"1344") M(22,"1408") M(23,"1472") \
    M(24,"1536") M(25,"1600") M(26,"1664") M(27,"1728") M(28,"1792") M(29,"1856") M(30,"1920") M(31,"1984")
// MFMA must not hoist above the wait; ALU/SALU/DS may (0x1|0x2|0x4|0x80|0x100)
#define WAITV(N) do { asm volatile("s_waitcnt vmcnt(" #N ")" ::: "memory"); \
                      __builtin_amdgcn_sched_barrier(0x187); } while (0)
#define CHUNK(c) do { _Pragma("unroll") \
    for (int e = 0; e < 8; ++e) { \
        bf16x8 bfrag = *(const bf16x8*)(wl + ((c) * 8 + e) * 32); \
        acc = mfma16(as_bf16x8(AR[(c) * 8 + e]), bfrag, acc); } } while (0)

// relay rows [r0,r1): coherent (sc0 sc1) load from L3 -> plain store (dirty in LOCAL L2)
__device__ __forceinline__ void relay_copy(const bf16_t* __restrict__ src,
                                           bf16_t* __restrict__ dst,
                                           int r0, int r1, int tid) {
    const size_t base = (size_t)r0 * NHID;
    const size_t nby  = (size_t)(r1 - r0) * NHID * sizeof(bf16_t);
    const char* s = (const char*)(src + base);
    char* d = (char*)(dst + base);
    for (size_t o = (size_t)tid * 16; o < nby; o += (size_t)512 * 16) {
        u32x4 v;
        asm volatile("global_load_dwordx4 %0, %1, off sc0 sc1" : "=v"(v) : "v"(s + o));
        asm volatile("s_waitcnt vmcnt(0)" ::: "memory");
        *(u32x4*)(d + o) = v;
    }
}

__device__ __forceinline__ void global_barrier(unsigned int* flags, unsigned int* goarr,
                                               unsigned int round, int tid) {
    if (tid == 0)
        __hip_atomic_store(&flags[blockIdx.x * 16], round,
                           __ATOMIC_RELAXED, __HIP_MEMORY_SCOPE_AGENT);
    if (blockIdx.x == 0) {
        if (tid < NBLK)
            while (__hip_atomic_load(&flags[tid * 16],
                                     __ATOMIC_RELAXED, __HIP_MEMORY_SCOPE_AGENT) < round)
                __builtin_amdgcn_s_sleep(2);
        __syncthreads();
        if (tid < NGO)
            __hip_atomic_store(&goarr[tid * 16], round,
                               __ATOMIC_RELAXED, __HIP_MEMORY_SCOPE_AGENT);
    } else {
        if (tid == 0)
            while (__hip_atomic_load(&goarr[(blockIdx.x & (NGO - 1)) * 16],
                                     __ATOMIC_RELAXED, __HIP_MEMORY_SCOPE_AGENT) < round)
                __builtin_amdgcn_s_sleep(2);
        __syncthreads();
    }
}

// intra-XCD barrier — flags via AGENT atomics (coherence point), proven protocol (R6)
__device__ __forceinline__ void local_barrier(unsigned int* lflags, unsigned int* lgo,
                                              int xcd, int lrank, int cnt,
                                              unsigned int round, int tid) {
    if (tid == 0)
        __hip_atomic_store(&lflags[(xcd * 256 + lrank) * 16], round,
                           __ATOMIC_RELAXED, __HIP_MEMORY_SCOPE_AGENT);
    if (lrank == 0) {
        if (tid < cnt)
            while (__hip_atomic_load(&lflags[(xcd * 256 + tid) * 16],
                                     __ATOMIC_RELAXED, __HIP_MEMORY_SCOPE_AGENT) < round)
                __builtin_amdgcn_s_sleep(1);
        __syncthreads();
        if (tid == 0)
            __hip_atomic_store(&lgo[xcd * 16], round,
                               __ATOMIC_RELAXED, __HIP_MEMORY_SCOPE_AGENT);
    } else {
        if (tid == 0)
            while (__hip_atomic_load(&lgo[xcd * 16],
                                     __ATOMIC_RELAXED, __HIP_MEMORY_SCOPE_AGENT) < round)
                __builtin_amdgcn_s_sleep(1);
        __syncthreads();
    }
}

__global__ __launch_bounds__(512, 1) void k_rhn_persist(
    const float* __restrict__ hidden, const float* __restrict__ s_mask,
    const float* __restrict__ Wih, const float* __restrict__ bih,
    const float* __restrict__ Wit, const float* __restrict__ bitv,
    const float* __restrict__ Wh,  const float* __restrict__ bh,
    const float* __restrict__ Wt,  const float* __restrict__ bt,
    const bf16_t* __restrict__ xm,
    bf16_t* __restrict__ smbA, bf16_t* __restrict__ smbB,
    bf16_t* __restrict__ mir,           // per-XCD mirrors: [8][2] panels
    unsigned int* __restrict__ flags, unsigned int* __restrict__ goarr,
    unsigned int* __restrict__ xcdcnt,  // 8 slots, 64B apart
    unsigned int* __restrict__ lflags,  // [8][256] slots, 64B apart
    unsigned int* __restrict__ lgo,     // 8 slots, 64B apart
    float* __restrict__ out)
{
    extern __shared__ bf16_t wlds[];   // 48 x WSTRIDE bf16 = 97.5 KB
    __shared__ int sxcd, slrank, scnt;
    const int tid  = threadIdx.x;
    const int lane = tid & 63;
    const int wv   = tid >> 6;          // 0..7
    const int c0   = blockIdx.x * CPB;

    if (tid == 0) {
        int x = get_xcc_id();
        sxcd = x;
        slrank = (int)__hip_atomic_fetch_add(&xcdcnt[x * 16], 1u,
                                             __ATOMIC_RELAXED, __HIP_MEMORY_SCOPE_AGENT);
    }

    // ---- stage weight slice f32 -> bf16 LDS (once) ----
    for (int row_id = wv; row_id < 48; row_id += 8) {
        const int m = row_id >> 3, r = row_id & 7;
        const int c = c0 + (r & 3);
        const float* src;
        if (m == 0) src = ((r < 4) ? Wih : Wit) + (size_t)c * NHID;
        else        src = ((r < 4) ? Wh  : Wt ) + ((size_t)(m - 1) * NHID + c) * NHID;
        bf16_t* dst = wlds + (size_t)row_id * WSTRIDE;
        const int e = lane * 16;
        #pragma unroll
        for (int u = 0; u < 16; ++u)
            dst[e + u] = __float2bfloat16(src[e + u]);
    }

    // ---- per-lane roles & register state ----
    const int lr = lane & 15;
    const int kg = lane >> 4;
    const int wbase = wv * 16;          // 16 batch rows per wave
    const int cc = c0 + (lr & 3);
    const bool isT = (lr & 4) != 0;

    float biasl[NDEPTH];
    #pragma unroll
    for (int l = 0; l < NDEPTH; ++l) {
        float bb = isT ? bt[(size_t)l * NHID + cc] : bh[(size_t)l * NHID + cc];
        if (l == 0) bb += isT ? bitv[cc] : bih[cc];
        biasl[l] = bb;
    }

    float sreg[4], smk[4];
    #pragma unroll
    for (int j = 0; j < 4; ++j) {
        const int row = wbase + kg * 4 + j;
        sreg[j] = hidden[(size_t)row * NHID + cc];
        smk[j]  = s_mask[(size_t)row * NHID + cc];
    }

    __syncthreads();   // LDS weights + sxcd/slrank ready
    const int xcd = sxcd, lrank = slrank;

    // ---- startup: global barrier (all blocks registered), then learn local count ----
    unsigned int round = 1;
    global_barrier(flags, goarr, round, tid);
    if (tid == 0)
        scnt = (int)__hip_atomic_load(&xcdcnt[xcd * 16],
                                      __ATOMIC_RELAXED, __HIP_MEMORY_SCOPE_AGENT);
    __syncthreads();
    const int cnt = scnt;
    const int r0r = (lrank * BATCH) / cnt;
    const int r1r = ((lrank + 1) * BATCH) / cnt;

    // ---- seed mirror[xcd][0] from smbA, local barrier ----
    relay_copy(smbA, mir + (size_t)(xcd * 2 + 0) * PANEL, r0r, r1r, tid);
    __syncthreads();   // drain relay stores before flagging
    local_barrier(lflags, lgo, xcd, lrank, cnt, round, tid);

    const size_t aoff = (size_t)(wbase + lr) * NHID + kg * 8;
    int par = 0;

    for (int t = 0; t < SEQ; ++t) {
        const bf16_t* xmt = xm + (size_t)t * BATCH * NHID;
        #pragma unroll
        for (int l = 0; l < NDEPTH; ++l) {
            bf16_t* An = par ? smbA : smbB;
            f32x4 acc = {0.f, 0.f, 0.f, 0.f};
            u32x4 AR[32];

            {   // recurrent path: sm @ [Wh_l | Wt_l]^T — A from this XCD's L2 mirror
                const bf16_t* aptr = mir + (size_t)(xcd * 2 + par) * PANEL + aoff;
                const bf16_t* wl = wlds + (size_t)((1 + l) * 8 + (lane & 7)) * WSTRIDE + kg * 8;
                ISSUE32(LDU)
                WAITV(24); CHUNK(0);
                WAITV(16); CHUNK(1);
                WAITV(8);  CHUNK(2);
                WAITV(0);  CHUNK(3);
            }
            if (l == 0) {   // input path folded in: x_t @ [Wih | Wit]^T (cached loads)
                const bf16_t* xptr = xmt + aoff;
                const bf16_t* wl = wlds + (size_t)(lane & 7) * WSTRIDE + kg * 8;
                ISSUE32(LDCQ)
                WAITV(24); CHUNK(0);
                WAITV(16); CHUNK(1);
                WAITV(8);  CHUNK(2);
                WAITV(0);  CHUNK(3);
            }

            // ---- epilogue: C col = lane&15, row = (lane>>4)*4 + j ----
            const float vb = biasl[l];
            #pragma unroll
            for (int j = 0; j < 4; ++j) {
                float v = acc[j] + vb;
                float o = __int_as_float(
                    __builtin_amdgcn_ds_swizzle(__float_as_int(v), 0x101F)); // lane^4: H<->T
                float Hv = tanhf(v);
                float Tv = 1.f / (1.f + __expf(-o));
                float sv = sreg[j];
                float sn = (Hv - sv) * Tv + sv;
                sreg[j] = sn;
                const int row = wbase + kg * 4 + j;

                // pack 4 cols x bf16 (lanes lr=0..3) into one 8B store from lane lr==0
                uint32_t a  = (uint32_t)f32_to_bf16_bits(sn * smk[j]);
                uint32_t b  = __builtin_amdgcn_ds_swizzle(a, 0x041F);   // lane^1
                uint32_t w  = (a & 0xffffu) | (b << 16);
                uint32_t c2 = __builtin_amdgcn_ds_swizzle(w, 0x081F);   // lane^2
                if (lr == 0) {
                    uint64_t q = (uint64_t)w | ((uint64_t)c2 << 32);
                    __hip_atomic_store((uint64_t*)(An + (size_t)row * NHID + c0), q,
                                       __ATOMIC_RELAXED, __HIP_MEMORY_SCOPE_AGENT);
                }
                if (l == NDEPTH - 1 && lr < 4) {     // out: plain cached stores
                    out[((size_t)t * BATCH + row) * NHID + cc] = sn;
                    if (t == SEQ - 1)
                        out[(size_t)SEQ * BATCH * NHID + (size_t)row * NHID + cc] = sn;
                }
            }

            if (t == SEQ - 1 && l == NDEPTH - 1) break;   // nothing consumes the last state

            // ---- global barrier, then XCD-local relay + local barrier ----
            ++round;
            __syncthreads();   // drain epilogue stores (waitcnt vmcnt(0) before s_barrier)
            global_barrier(flags, goarr, round, tid);
            relay_copy(An, mir + (size_t)(xcd * 2 + (par ^ 1)) * PANEL, r0r, r1r, tid);
            __syncthreads();   // drain relay stores into local L2
            local_barrier(lflags, lgo, xcd, lrank, cnt, round, tid);
            par ^= 1;
        }
    }
}

extern "C" void kernel_launch(void* const* d_in, const int* in_sizes, int n_in,
                              void* d_out, int out_size, void* d_ws, size_t ws_size,
                              hipStream_t stream) {
    (void)in_sizes; (void)n_in; (void)out_size; (void)ws_size;

    const float* inp    = (const float*)d_in[0];
    const float* hidden = (const float*)d_in[1];
    const float* h_mask = (const float*)d_in[2];
    const float* s_mask = (const float*)d_in[3];
    const float* Wih    = (const float*)d_in[4];
    const float* bih    = (const float*)d_in[5];
    const float* Wit    = (const float*)d_in[6];
    const float* bitv   = (const float*)d_in[7];
    const float* Wh     = (const float*)d_in[8];
    const float* bh     = (const float*)d_in[9];
    const float* Wt     = (const float*)d_in[10];
    const float* bt     = (const float*)d_in[11];
    float* out = (float*)d_out;

    // ws: xm 52.4MB | smbA | smbB | mirrors 8x2 panels (8MB) | control
    bf16_t* xm   = (bf16_t*)d_ws;
    bf16_t* smbA = xm + (size_t)SEQ * BATCH * NHID;
    bf16_t* smbB = smbA + PANEL;
    bf16_t* mir  = smbB + PANEL;
    unsigned int* ctl    = (unsigned int*)(mir + (size_t)16 * PANEL);
    unsigned int* flags  = ctl;                    // 256*16
    unsigned int* goarr  = flags  + NBLK * 16;     // 32*16
    unsigned int* xcdcnt = goarr  + NGO * 16;      // 8*16
    unsigned int* lflags = xcdcnt + 8 * 16;        // 8*256*16
    unsigned int* lgo    = lflags + 8 * 256 * 16;  // 8*16
    const size_t ctl_u32 = (size_t)(NBLK * 16 + NGO * 16 + 8 * 16 + 8 * 256 * 16 + 8 * 16);

    hipMemsetAsync(ctl, 0, ctl_u32 * sizeof(unsigned int), stream);
    k_prep_xm<<<dim3(2048), dim3(256), 0, stream>>>(inp, h_mask, xm, SEQ * BATCH * NHID);
    k_init_smb<<<dim3(64), dim3(256), 0, stream>>>(hidden, s_mask, smbA, BATCH * NHID);

    const size_t ldsBytes = (size_t)48 * WSTRIDE * sizeof(bf16_t);  // 97.5 KB
    hipFuncSetAttribute((const void*)k_rhn_persist,
                        hipFuncAttributeMaxDynamicSharedMemorySize, (int)ldsBytes);
    k_rhn_persist<<<dim3(NBLK), dim3(512), ldsBytes, stream>>>(
        hidden, s_mask, Wih, bih, Wit, bitv, Wh, bh, Wt, bt,
        xm, smbA, smbB, mir, flags, goarr, xcdcnt, lflags, lgo, out);
}

// Round 11
// 11374.154 us; speedup vs baseline: 1.2494x; 1.2494x over previous
//
#include <hip/hip_runtime.h>
#include <hip/hip_bf16.h>
#include <stdint.h>

#define SEQ    200
#define BATCH  128
#define NHID   1024
#define NDEPTH 5
#define NBLK   256            // persistent blocks == CUs
#define CPB    4              // hidden columns owned per block
#define WSTRIDE (NHID + 16)   // LDS row stride (bf16): breaks power-of-2 bank aliasing

typedef __bf16 bf16x8 __attribute__((ext_vector_type(8)));
typedef float  f32x4  __attribute__((ext_vector_type(4)));
typedef uint32_t u32x4 __attribute__((ext_vector_type(4)));
typedef __hip_bfloat16 bf16_t;

__device__ __forceinline__ f32x4 mfma16(bf16x8 a, bf16x8 b, f32x4 c) {
    return __builtin_amdgcn_mfma_f32_16x16x32_bf16(a, b, c, 0, 0, 0);
}
__device__ __forceinline__ bf16x8 as_bf16x8(u32x4 x) {
    union { u32x4 u; bf16x8 b; } t; t.u = x; return t.b;
}
__device__ __forceinline__ unsigned short f32_to_bf16_bits(float f) {
    uint32_t x = __float_as_uint(f);
    uint32_t r = ((x >> 16) & 1u) + 0x7fffu;   // RNE
    return (unsigned short)((x + r) >> 16);
}

__global__ void k_prep_xm(const float* __restrict__ inp, const float* __restrict__ h_mask,
                          bf16_t* __restrict__ xm, int n) {
    for (int i = blockIdx.x * blockDim.x + threadIdx.x; i < n; i += gridDim.x * blockDim.x) {
        int r = i & (BATCH * NHID - 1);
        xm[i] = __float2bfloat16(inp[i] * h_mask[r]);
    }
}

__global__ void k_init_smb(const float* __restrict__ hidden, const float* __restrict__ s_mask,
                           bf16_t* __restrict__ smb, int n) {
    for (int i = blockIdx.x * blockDim.x + threadIdx.x; i < n; i += gridDim.x * blockDim.x)
        smb[i] = __float2bfloat16(hidden[i] * s_mask[i]);
}

// batched A loads: sc0 sc1 (coherence-point) for smb, plain cached for xm
#define LDU(i, OFF) asm volatile("global_load_dwordx4 %0, %1, off offset:" OFF " sc0 sc1" \
                                 : "=v"(AR[i]) : "v"(aptr));
#define LDCQ(i, OFF) asm volatile("global_load_dwordx4 %0, %1, off offset:" OFF \
                                 : "=v"(AR[i]) : "v"(xptr));
#define ISSUE32(M) \
    M(0,"0")    M(1,"64")   M(2,"128")  M(3,"192")  M(4,"256")  M(5,"320")  M(6,"384")  M(7,"448") \
    M(8,"512")  M(9,"576")  M(10,"640") M(11,"704") M(12,"768") M(13,"832") M(14,"896") M(15,"960") \
    M(16,"1024") M(17,"1088") M(18,"1152") M(19,"1216") M(20,"1280") M(21,"1344") M(22,"1408") M(23,"1472") \
    M(24,"1536") M(25,"1600") M(26,"1664") M(27,"1728") M(28,"1792") M(29,"1856") M(30,"1920") M(31,"1984")
// MFMA must not hoist above the wait; ALU/SALU/DS may (0x1|0x2|0x4|0x80|0x100)
#define WAITV(N) do { asm volatile("s_waitcnt vmcnt(" #N ")" ::: "memory"); \
                      __builtin_amdgcn_sched_barrier(0x187); } while (0)
#define CHUNK(c) do { _Pragma("unroll") \
    for (int e = 0; e < 8; ++e) { \
        bf16x8 bfrag = *(const bf16x8*)(wl + ((c) * 8 + e) * 32); \
        acc = mfma16(as_bf16x8(AR[(c) * 8 + e]), bfrag, acc); } } while (0)

__global__ __launch_bounds__(512, 2) void k_rhn_persist(
    const float* __restrict__ hidden, const float* __restrict__ s_mask,
    const float* __restrict__ Wih, const float* __restrict__ bih,
    const float* __restrict__ Wit, const float* __restrict__ bitv,
    const float* __restrict__ Wh,  const float* __restrict__ bh,
    const float* __restrict__ Wt,  const float* __restrict__ bt,
    const bf16_t* __restrict__ xm,
    bf16_t* __restrict__ smbA, bf16_t* __restrict__ smbB,
    unsigned int* __restrict__ flags,   // 256 slots, 64B apart
    float* __restrict__ out)
{
    extern __shared__ bf16_t wlds[];   // 48 x WSTRIDE bf16 = 97.5 KB
    const int tid  = threadIdx.x;
    const int lane = tid & 63;
    const int wv   = tid >> 6;          // 0..7
    const int c0   = blockIdx.x * CPB;

    // ---- stage weight slice f32 -> bf16 LDS (once) ----
    for (int row_id = wv; row_id < 48; row_id += 8) {
        const int m = row_id >> 3, r = row_id & 7;
        const int c = c0 + (r & 3);
        const float* src;
        if (m == 0) src = ((r < 4) ? Wih : Wit) + (size_t)c * NHID;
        else        src = ((r < 4) ? Wh  : Wt ) + ((size_t)(m - 1) * NHID + c) * NHID;
        bf16_t* dst = wlds + (size_t)row_id * WSTRIDE;
        const int e = lane * 16;
        #pragma unroll
        for (int u = 0; u < 16; ++u)
            dst[e + u] = __float2bfloat16(src[e + u]);
    }

    // ---- per-lane roles & register state ----
    const int lr = lane & 15;
    const int kg = lane >> 4;
    const int wbase = wv * 16;          // 16 batch rows per wave
    const int cc = c0 + (lr & 3);
    const bool isT = (lr & 4) != 0;

    float biasl[NDEPTH];
    #pragma unroll
    for (int l = 0; l < NDEPTH; ++l) {
        float bb = isT ? bt[(size_t)l * NHID + cc] : bh[(size_t)l * NHID + cc];
        if (l == 0) bb += isT ? bitv[cc] : bih[cc];
        biasl[l] = bb;
    }

    float sreg[4], smk[4];
    #pragma unroll
    for (int j = 0; j < 4; ++j) {
        const int row = wbase + kg * 4 + j;
        sreg[j] = hidden[(size_t)row * NHID + cc];
        smk[j]  = s_mask[(size_t)row * NHID + cc];
    }

    __syncthreads();   // LDS weights ready

    const size_t aoff = (size_t)(wbase + lr) * NHID + kg * 8;
    unsigned int rv = 0;
    int par = 0;

    for (int t = 0; t < SEQ; ++t) {
        const bf16_t* xmt = xm + (size_t)t * BATCH * NHID;
        #pragma unroll
        for (int l = 0; l < NDEPTH; ++l) {
            const bf16_t* Abuf = par ? smbB : smbA;
            bf16_t*       An   = par ? smbA : smbB;
            f32x4 acc = {0.f, 0.f, 0.f, 0.f};
            u32x4 AR[32];

            {   // recurrent path: sm @ [Wh_l | Wt_l]^T  — 32 coherent b128 loads in flight
                const bf16_t* aptr = Abuf + aoff;
                const bf16_t* wl = wlds + (size_t)((1 + l) * 8 + (lane & 7)) * WSTRIDE + kg * 8;
                ISSUE32(LDU)
                WAITV(24); CHUNK(0);
                WAITV(16); CHUNK(1);
                WAITV(8);  CHUNK(2);
                WAITV(0);  CHUNK(3);
            }
            if (l == 0) {   // input path folded in: x_t @ [Wih | Wit]^T (cached loads)
                const bf16_t* xptr = xmt + aoff;
                const bf16_t* wl = wlds + (size_t)(lane & 7) * WSTRIDE + kg * 8;
                ISSUE32(LDCQ)
                WAITV(24); CHUNK(0);
                WAITV(16); CHUNK(1);
                WAITV(8);  CHUNK(2);
                WAITV(0);  CHUNK(3);
            }

            // ---- epilogue: C col = lane&15, row = (lane>>4)*4 + j ----
            const float vb = biasl[l];
            #pragma unroll
            for (int j = 0; j < 4; ++j) {
                float v = acc[j] + vb;
                float o = __int_as_float(
                    __builtin_amdgcn_ds_swizzle(__float_as_int(v), 0x101F)); // lane^4: H<->T
                float Hv = tanhf(v);
                float Tv = 1.f / (1.f + __expf(-o));
                float sv = sreg[j];
                float sn = (Hv - sv) * Tv + sv;
                sreg[j] = sn;
                const int row = wbase + kg * 4 + j;

                // pack 4 cols x bf16 (lanes lr=0..3) into one 8B store from lane lr==0
                uint32_t a  = (uint32_t)f32_to_bf16_bits(sn * smk[j]);
                uint32_t b  = __builtin_amdgcn_ds_swizzle(a, 0x041F);   // lane^1
                uint32_t w  = (a & 0xffffu) | (b << 16);
                uint32_t c2 = __builtin_amdgcn_ds_swizzle(w, 0x081F);   // lane^2
                if (lr == 0) {
                    uint64_t q = (uint64_t)w | ((uint64_t)c2 << 32);
                    __hip_atomic_store((uint64_t*)(An + (size_t)row * NHID + c0), q,
                                       __ATOMIC_RELAXED, __HIP_MEMORY_SCOPE_AGENT);
                }
                if (l == NDEPTH - 1 && lr < 4) {     // out: plain cached stores
                    out[((size_t)t * BATCH + row) * NHID + cc] = sn;
                    if (t == SEQ - 1)
                        out[(size_t)SEQ * BATCH * NHID + (size_t)row * NHID + cc] = sn;
                }
            }

            // ---- device-wide barrier: flat all-to-all (single delta vs R6) ----
            ++rv;
            if (!(t == SEQ - 1 && l == NDEPTH - 1)) {
                __syncthreads();   // emits s_waitcnt vmcnt(0): block's stores acked at L3
                if (tid == 0)
                    __hip_atomic_store(&flags[blockIdx.x * 16], rv,
                                       __ATOMIC_RELAXED, __HIP_MEMORY_SCOPE_AGENT);
                if (tid < 64) {    // wave 0 polls all 256 flags: 4 loads/lane
                    const unsigned int* p0 = &flags[tid * 16];
                    const unsigned int* p1 = &flags[(64 + tid) * 16];
                    const unsigned int* p2 = &flags[(128 + tid) * 16];
                    const unsigned int* p3 = &flags[(192 + tid) * 16];
                    for (;;) {
                        unsigned int f0 = __hip_atomic_load(p0, __ATOMIC_RELAXED,
                                                            __HIP_MEMORY_SCOPE_AGENT);
                        unsigned int f1 = __hip_atomic_load(p1, __ATOMIC_RELAXED,
                                                            __HIP_MEMORY_SCOPE_AGENT);
                        unsigned int f2 = __hip_atomic_load(p2, __ATOMIC_RELAXED,
                                                            __HIP_MEMORY_SCOPE_AGENT);
                        unsigned int f3 = __hip_atomic_load(p3, __ATOMIC_RELAXED,
                                                            __HIP_MEMORY_SCOPE_AGENT);
                        if (__all(f0 >= rv && f1 >= rv && f2 >= rv && f3 >= rv)) break;
                        __builtin_amdgcn_s_sleep(2);
                    }
                }
                __syncthreads();   // release other waves once wave 0 saw all flags
            }
            par ^= 1;
        }
    }
}

extern "C" void kernel_launch(void* const* d_in, const int* in_sizes, int n_in,
                              void* d_out, int out_size, void* d_ws, size_t ws_size,
                              hipStream_t stream) {
    (void)in_sizes; (void)n_in; (void)out_size; (void)ws_size;

    const float* inp    = (const float*)d_in[0];
    const float* hidden = (const float*)d_in[1];
    const float* h_mask = (const float*)d_in[2];
    const float* s_mask = (const float*)d_in[3];
    const float* Wih    = (const float*)d_in[4];
    const float* bih    = (const float*)d_in[5];
    const float* Wit    = (const float*)d_in[6];
    const float* bitv   = (const float*)d_in[7];
    const float* Wh     = (const float*)d_in[8];
    const float* bh     = (const float*)d_in[9];
    const float* Wt     = (const float*)d_in[10];
    const float* bt     = (const float*)d_in[11];
    float* out = (float*)d_out;

    // ws layout: xm (bf16, 52.4MB) | smbA | smbB | flags
    bf16_t* xm   = (bf16_t*)d_ws;
    bf16_t* smbA = xm + (size_t)SEQ * BATCH * NHID;
    bf16_t* smbB = smbA + (size_t)BATCH * NHID;
    unsigned int* flags = (unsigned int*)(smbB + (size_t)BATCH * NHID);

    hipMemsetAsync(flags, 0, NBLK * 16 * sizeof(unsigned int), stream);
    k_prep_xm<<<dim3(2048), dim3(256), 0, stream>>>(inp, h_mask, xm, SEQ * BATCH * NHID);
    k_init_smb<<<dim3(64), dim3(256), 0, stream>>>(hidden, s_mask, smbA, BATCH * NHID);

    const size_t ldsBytes = (size_t)48 * WSTRIDE * sizeof(bf16_t);  // 97.5 KB
    hipFuncSetAttribute((const void*)k_rhn_persist,
                        hipFuncAttributeMaxDynamicSharedMemorySize, (int)ldsBytes);
    k_rhn_persist<<<dim3(NBLK), dim3(512), ldsBytes, stream>>>(
        hidden, s_mask, Wih, bih, Wit, bitv, Wh, bh, Wt, bt,
        xm, smbA, smbB, flags, out);
}

// Round 14
// 7643.768 us; speedup vs baseline: 1.8592x; 1.4880x over previous
//
#include <hip/hip_runtime.h>
#include <hip/hip_bf16.h>
#include <stdint.h>

#define SEQ    200
#define BATCH  128
#define NHID   1024
#define NDEPTH 5
#define NBLK   256
#define GRP_BLK 128                     // blocks per batch-group (G=2)
#define CPB    8                        // hidden columns owned per block
#define PANEL  ((size_t)BATCH * NHID)
#define SB     (SEQ * BATCH)            // 25600 flat rows

typedef __bf16 bf16x8 __attribute__((ext_vector_type(8)));
typedef float  f32x4  __attribute__((ext_vector_type(4)));
typedef uint32_t u32x4 __attribute__((ext_vector_type(4)));
typedef __hip_bfloat16 bf16_t;

__device__ __forceinline__ f32x4 mfma16(bf16x8 a, bf16x8 b, f32x4 c) {
    return __builtin_amdgcn_mfma_f32_16x16x32_bf16(a, b, c, 0, 0, 0);
}
__device__ __forceinline__ bf16x8 as_bf16x8(u32x4 x) {
    union { u32x4 u; bf16x8 b; } t; t.u = x; return t.b;
}
__device__ __forceinline__ unsigned short f32_to_bf16_bits(float f) {
    uint32_t x = __float_as_uint(f);
    uint32_t r = ((x >> 16) & 1u) + 0x7fffu;   // RNE
    return (unsigned short)((x + r) >> 16);
}
template<int PAT>
__device__ __forceinline__ float swzf(float v) {
    return __int_as_float(__builtin_amdgcn_ds_swizzle(__float_as_int(v), PAT));
}
template<int PAT>
__device__ __forceinline__ uint32_t swzu(uint32_t v) {
    return (uint32_t)__builtin_amdgcn_ds_swizzle((int)v, PAT);
}

__global__ void k_cast_bf16(const float* __restrict__ src, bf16_t* __restrict__ dst, int n) {
    for (int i = blockIdx.x * blockDim.x + threadIdx.x; i < n; i += gridDim.x * blockDim.x)
        dst[i] = __float2bfloat16(src[i]);
}

__global__ void k_init_smb(const float* __restrict__ hidden, const float* __restrict__ s_mask,
                           bf16_t* __restrict__ smb, int n) {
    for (int i = blockIdx.x * blockDim.x + threadIdx.x; i < n; i += gridDim.x * blockDim.x)
        smb[i] = __float2bfloat16(hidden[i] * s_mask[i]);
}

// ---------- pre-pass: H/T = bf16(inp*h_mask) @ Wih/Wit^T + bias -> fp16 ----------
// Compiler-scheduled (no inline asm). Mirrors R1's proven tile: grid(16, 800),
// 4 waves in 2x2; wave = 16 rows x 32 cols, H and T both (4 accumulators).
__global__ __launch_bounds__(256) void k_ht(
    const float* __restrict__ inp, const float* __restrict__ h_mask,
    const bf16_t* __restrict__ Wihb, const float* __restrict__ bih,
    const bf16_t* __restrict__ Witb, const float* __restrict__ bitv,
    _Float16* __restrict__ ht)
{
    const int lane = threadIdx.x & 63;
    const int w    = threadIdx.x >> 6;
    const int r0   = blockIdx.y * 32 + (w >> 1) * 16;
    const int c0   = blockIdx.x * 64 + (w & 1) * 32;
    const int lr   = lane & 15;
    const int kg   = lane >> 4;

    f32x4 aH0 = {0,0,0,0}, aH1 = {0,0,0,0}, aT0 = {0,0,0,0}, aT1 = {0,0,0,0};
    const int R = r0 + lr;
    const float* ap = inp + (size_t)R * NHID + kg * 8;
    const float* mp = h_mask + (size_t)(R & 127) * NHID + kg * 8;
    const bf16_t* Bh = Wihb + (size_t)(c0 + lr) * NHID + kg * 8;
    const bf16_t* Bt = Witb + (size_t)(c0 + lr) * NHID + kg * 8;

    for (int k = 0; k < NHID; k += 32) {
        f32x4 x0 = *(const f32x4*)(ap + k), x1 = *(const f32x4*)(ap + k + 4);
        f32x4 m0 = *(const f32x4*)(mp + k), m1 = *(const f32x4*)(mp + k + 4);
        union { bf16_t h[8]; bf16x8 v; } af;
        #pragma unroll
        for (int q = 0; q < 4; ++q) {
            af.h[q]     = __float2bfloat16(x0[q] * m0[q]);
            af.h[q + 4] = __float2bfloat16(x1[q] * m1[q]);
        }
        bf16x8 bh0 = *(const bf16x8*)(Bh + k);
        bf16x8 bh1 = *(const bf16x8*)(Bh + (size_t)16 * NHID + k);
        bf16x8 bt0 = *(const bf16x8*)(Bt + k);
        bf16x8 bt1 = *(const bf16x8*)(Bt + (size_t)16 * NHID + k);
        aH0 = mfma16(af.v, bh0, aH0);
        aH1 = mfma16(af.v, bh1, aH1);
        aT0 = mfma16(af.v, bt0, aT0);
        aT1 = mfma16(af.v, bt1, aT1);
    }

    const int n0 = c0 + lr, n1 = n0 + 16;
    #pragma unroll
    for (int j = 0; j < 4; ++j) {
        const int R2 = r0 + kg * 4 + j;
        const int t = R2 >> 7, b = R2 & 127;
        _Float16* hrow = ht + ((size_t)(t * 2 + 0) * BATCH + b) * NHID;
        _Float16* trow = ht + ((size_t)(t * 2 + 1) * BATCH + b) * NHID;
        hrow[n0] = (_Float16)(aH0[j] + bih[n0]);
        hrow[n1] = (_Float16)(aH1[j] + bih[n1]);
        trow[n0] = (_Float16)(aT0[j] + bitv[n0]);
        trow[n1] = (_Float16)(aT1[j] + bitv[n1]);
    }
}

// batched 16B A loads: sc0 sc1 (coherence point) for the state panel
#define LDU(i, OFF)  asm volatile("global_load_dwordx4 %0, %1, off offset:" OFF " sc0 sc1" \
                                  : "=v"(AR[i]) : "v"(aptr));
#define ISSUE32(M) \
    M(0,"0")    M(1,"64")   M(2,"128")  M(3,"192")  M(4,"256")  M(5,"320")  M(6,"384")  M(7,"448") \
    M(8,"512")  M(9,"576")  M(10,"640") M(11,"704") M(12,"768") M(13,"832") M(14,"896") M(15,"960") \
    M(16,"1024") M(17,"1088") M(18,"1152") M(19,"1216") M(20,"1280") M(21,"1344") M(22,"1408") M(23,"1472") \
    M(24,"1536") M(25,"1600") M(26,"1664") M(27,"1728") M(28,"1792") M(29,"1856") M(30,"1920") M(31,"1984")
// MFMA must not hoist above the wait; ALU/SALU/DS may (0x1|0x2|0x4|0x80|0x100)
#define WAITV(N) do { asm volatile("s_waitcnt vmcnt(" #N ")" ::: "memory"); \
                      __builtin_amdgcn_sched_barrier(0x187); } while (0)
// B from LDS row (2048B/row), 16B-granular XOR spreads 16 rows across bank-quads
#define CHUNK_LDS(c) do { _Pragma("unroll") \
    for (int e = 0; e < 8; ++e) { \
        const int off = (kg * 16 + ((c) * 8 + e) * 64) ^ xmask; \
        bf16x8 bf = *(const bf16x8*)(rowb + off); \
        acc = mfma16(as_bf16x8(AR[(c) * 8 + e]), bf, acc); } } while (0)

// 256 blocks x 256 threads (4 waves x 16 rows = 64 rows/group). Group g = bid>>7 owns
// rows [64g, 64g+64); block-in-group gb owns cols [8gb, 8gb+8): 16 gate-cols = full
// MFMA N-tile (lr<8 -> H col c0+lr, lr>=8 -> T col c0+lr-8). LDS: ALL 5 layer pairs,
// 80 rows x 2048B = 160 KB exactly, XOR bank spread. No streamed-B anywhere.
__global__ __launch_bounds__(256, 1) void k_rhn_persist(
    const float* __restrict__ hidden, const float* __restrict__ s_mask,
    const float* __restrict__ Wh,  const float* __restrict__ bh,
    const float* __restrict__ Wt,  const float* __restrict__ bt,
    const _Float16* __restrict__ ht,
    bf16_t* __restrict__ smbA, bf16_t* __restrict__ smbB,
    unsigned int* __restrict__ flags,   // [2][128] slots, 64B apart
    float* __restrict__ out)
{
    extern __shared__ char wlds[];      // 80 rows x 2048 B = 163840 B
    const int tid  = threadIdx.x;
    const int lane = tid & 63;
    const int wv   = tid >> 6;          // 0..3
    const int g    = blockIdx.x >> 7;
    const int gb   = blockIdx.x & (GRP_BLK - 1);
    const int c0   = gb * CPB;
    const int lr   = lane & 15;
    const int kg   = lane >> 4;
    const int wbase = g * 64 + wv * 16;
    const int cc   = c0 + (lr & 7);
    const bool isT = lr >= 8;
    const int xmask = (lr & 7) << 4;

    // ---- stage ALL 5 recurrent pairs f32 -> bf16 LDS with 16B XOR placement ----
    for (int row = wv; row < 80; row += 4) {
        const int l = row >> 4, r = row & 15;
        const float* src = ((r < 8) ? Wh : Wt) + ((size_t)l * NHID + c0 + (r & 7)) * NHID;
        char* rb = wlds + (size_t)row * 2048;
        const int X = (r & 7) << 4;
        #pragma unroll
        for (int u = 0; u < 2; ++u) {
            union { bf16_t h[8]; u32x4 v; } pk;
            #pragma unroll
            for (int q = 0; q < 8; ++q)
                pk.h[q] = __float2bfloat16(src[lane * 16 + u * 8 + q]);
            *(u32x4*)(rb + ((lane * 32 + u * 16) ^ X)) = pk.v;
        }
    }

    // ---- per-lane state ----
    float biasl[NDEPTH];
    #pragma unroll
    for (int l = 0; l < NDEPTH; ++l)
        biasl[l] = isT ? bt[(size_t)l * NHID + cc] : bh[(size_t)l * NHID + cc];
    float sreg[4], smk[4];
    #pragma unroll
    for (int j = 0; j < 4; ++j) {
        const int row = wbase + kg * 4 + j;
        sreg[j] = hidden[(size_t)row * NHID + cc];
        smk[j]  = s_mask[(size_t)row * NHID + cc];
    }

    __syncthreads();   // LDS weights ready

    const size_t aoff = (size_t)(wbase + lr) * NHID + kg * 8;
    unsigned int rv = 0;
    int par = 0;

    for (int t = 0; t < SEQ; ++t) {
        #pragma unroll
        for (int l = 0; l < NDEPTH; ++l) {
            const bf16_t* Abuf = par ? smbB : smbA;
            bf16_t*       An   = par ? smbA : smbB;
            f32x4 acc = {0.f, 0.f, 0.f, 0.f};
            u32x4 AR[32];

            {   // recurrent GEMM: B fragments from LDS (R6-proven A-load pattern)
                const bf16_t* aptr = Abuf + aoff;
                const char* rowb = wlds + (size_t)(l * 16 + lr) * 2048;
                ISSUE32(LDU)
                WAITV(24); CHUNK_LDS(0);
                WAITV(16); CHUNK_LDS(1);
                WAITV(8);  CHUNK_LDS(2);
                WAITV(0);  CHUNK_LDS(3);
            }
            if (l == 0) {   // add precomputed input contribution (fp16, plain loads)
                const _Float16* hp = ht + (size_t)(t * 2 + (isT ? 1 : 0)) * PANEL + cc;
                #pragma unroll
                for (int j = 0; j < 4; ++j)
                    acc[j] += (float)hp[(size_t)(wbase + kg * 4 + j) * NHID];
            }

            // ---- epilogue: C col = lane&15 (gate-col), row = kg*4 + j ----
            const float vb = biasl[l];
            #pragma unroll
            for (int j = 0; j < 4; ++j) {
                float v = acc[j] + vb;
                float o = swzf<0x201F>(v);            // lane^8: H-pre <-> T-pre
                float Hv = tanhf(v);
                float Tv = 1.f / (1.f + __expf(-o));
                float sv = sreg[j];
                float sn = (Hv - sv) * Tv + sv;       // valid on H-lanes (lr<8)
                sreg[j] = sn;
                const int row = wbase + kg * 4 + j;

                // pack 8 cols x bf16 (lanes lr=0..7) into 16B on lane lr==0
                uint32_t a  = (uint32_t)f32_to_bf16_bits(sn * smk[j]);
                uint32_t b1 = swzu<0x041F>(a);                     // lane^1
                uint32_t w  = (a & 0xffffu) | (b1 << 16);
                uint32_t c2 = swzu<0x081F>(w);                     // lane^2
                uint32_t e1 = swzu<0x101F>(w);                     // lane^4
                uint32_t e2 = swzu<0x101F>(c2);
                if (lr == 0) {
                    uint64_t q0 = (uint64_t)w  | ((uint64_t)c2 << 32);
                    uint64_t q1 = (uint64_t)e1 | ((uint64_t)e2 << 32);
                    uint64_t* p = (uint64_t*)(An + (size_t)row * NHID + c0);
                    __hip_atomic_store(p,     q0, __ATOMIC_RELAXED, __HIP_MEMORY_SCOPE_AGENT);
                    __hip_atomic_store(p + 1, q1, __ATOMIC_RELAXED, __HIP_MEMORY_SCOPE_AGENT);
                }
                if (l == NDEPTH - 1 && lr < 8) {      // out: plain cached stores
                    out[((size_t)t * BATCH + row) * NHID + cc] = sn;
                    if (t == SEQ - 1)
                        out[(size_t)SEQ * BATCH * NHID + (size_t)row * NHID + cc] = sn;
                }
            }

            // ---- group-scoped flat all-to-all barrier (R11-proven protocol) ----
            ++rv;
            if (!(t == SEQ - 1 && l == NDEPTH - 1)) {
                __syncthreads();   // drains vmcnt: block's state stores acked
                if (tid == 0)
                    __hip_atomic_store(&flags[(g * GRP_BLK + gb) * 16], rv,
                                       __ATOMIC_RELAXED, __HIP_MEMORY_SCOPE_AGENT);
                if (tid < 64) {    // wave 0 polls the group's 128 flags: 2 loads/lane
                    const unsigned int* p0 = &flags[(g * GRP_BLK + lane) * 16];
                    const unsigned int* p1 = &flags[(g * GRP_BLK + 64 + lane) * 16];
                    for (;;) {
                        unsigned int f0 = __hip_atomic_load(p0, __ATOMIC_RELAXED,
                                                            __HIP_MEMORY_SCOPE_AGENT);
                        unsigned int f1 = __hip_atomic_load(p1, __ATOMIC_RELAXED,
                                                            __HIP_MEMORY_SCOPE_AGENT);
                        if (__all(f0 >= rv && f1 >= rv)) break;
                        __builtin_amdgcn_s_sleep(2);
                    }
                }
                __syncthreads();   // release other waves
            }
            par ^= 1;
        }
    }
}

extern "C" void kernel_launch(void* const* d_in, const int* in_sizes, int n_in,
                              void* d_out, int out_size, void* d_ws, size_t ws_size,
                              hipStream_t stream) {
    (void)in_sizes; (void)n_in; (void)out_size; (void)ws_size;

    const float* inp    = (const float*)d_in[0];
    const float* hidden = (const float*)d_in[1];
    const float* h_mask = (const float*)d_in[2];
    const float* s_mask = (const float*)d_in[3];
    const float* Wih    = (const float*)d_in[4];
    const float* bih    = (const float*)d_in[5];
    const float* Wit    = (const float*)d_in[6];
    const float* bitv   = (const float*)d_in[7];
    const float* Wh     = (const float*)d_in[8];
    const float* bh     = (const float*)d_in[9];
    const float* Wt     = (const float*)d_in[10];
    const float* bt     = (const float*)d_in[11];
    float* out = (float*)d_out;

    // ws: ht fp16 [S][2][B][HID] 104.9MB | Wihb 2MB | Witb 2MB | smbA | smbB | flags
    _Float16* ht   = (_Float16*)d_ws;
    bf16_t* Wihb   = (bf16_t*)(ht + (size_t)SEQ * 2 * PANEL);
    bf16_t* Witb   = Wihb + (size_t)NHID * NHID;
    bf16_t* smbA   = Witb + (size_t)NHID * NHID;
    bf16_t* smbB   = smbA + PANEL;
    unsigned int* flags = (unsigned int*)(smbB + PANEL);

    hipMemsetAsync(flags, 0, NBLK * 16 * sizeof(unsigned int), stream);
    k_cast_bf16<<<dim3(512), dim3(256), 0, stream>>>(Wih, Wihb, NHID * NHID);
    k_cast_bf16<<<dim3(512), dim3(256), 0, stream>>>(Wit, Witb, NHID * NHID);
    k_init_smb<<<dim3(64), dim3(256), 0, stream>>>(hidden, s_mask, smbA, BATCH * NHID);
    k_ht<<<dim3(NHID / 64, SB / 32), dim3(256), 0, stream>>>(
        inp, h_mask, Wihb, bih, Witb, bitv, ht);

    const size_t ldsBytes = (size_t)80 * 2048;   // 160 KB exactly
    hipFuncSetAttribute((const void*)k_rhn_persist,
                        hipFuncAttributeMaxDynamicSharedMemorySize, (int)ldsBytes);
    k_rhn_persist<<<dim3(NBLK), dim3(256), ldsBytes, stream>>>(
        hidden, s_mask, Wh, bh, Wt, bt, ht, smbA, smbB, flags, out);
}

// Round 15
// 7572.621 us; speedup vs baseline: 1.8766x; 1.0094x over previous
//
#include <hip/hip_runtime.h>
#include <hip/hip_bf16.h>
#include <stdint.h>

#define SEQ    200
#define BATCH  128
#define NHID   1024
#define NDEPTH 5
#define NBLK   256
#define GRP_BLK 128                     // blocks per batch-group (G=2)
#define CPB    8                        // hidden columns owned per block
#define PANEL  ((size_t)BATCH * NHID)
#define SB     (SEQ * BATCH)

typedef __bf16 bf16x8 __attribute__((ext_vector_type(8)));
typedef float  f32x4  __attribute__((ext_vector_type(4)));
typedef uint32_t u32x4 __attribute__((ext_vector_type(4)));
typedef __hip_bfloat16 bf16_t;

__device__ __forceinline__ f32x4 mfma16(bf16x8 a, bf16x8 b, f32x4 c) {
    return __builtin_amdgcn_mfma_f32_16x16x32_bf16(a, b, c, 0, 0, 0);
}
__device__ __forceinline__ bf16x8 as_bf16x8(u32x4 x) {
    union { u32x4 u; bf16x8 b; } t; t.u = x; return t.b;
}
__device__ __forceinline__ unsigned short f32_to_bf16_bits(float f) {
    uint32_t x = __float_as_uint(f);
    uint32_t r = ((x >> 16) & 1u) + 0x7fffu;   // RNE
    return (unsigned short)((x + r) >> 16);
}
template<int PAT>
__device__ __forceinline__ float swzf(float v) {
    return __int_as_float(__builtin_amdgcn_ds_swizzle(__float_as_int(v), PAT));
}
template<int PAT>
__device__ __forceinline__ uint32_t swzu(uint32_t v) {
    return (uint32_t)__builtin_amdgcn_ds_swizzle((int)v, PAT);
}

__global__ void k_cast_bf16(const float* __restrict__ src, bf16_t* __restrict__ dst, int n) {
    for (int i = blockIdx.x * blockDim.x + threadIdx.x; i < n; i += gridDim.x * blockDim.x)
        dst[i] = __float2bfloat16(src[i]);
}

__global__ void k_init_smb(const float* __restrict__ hidden, const float* __restrict__ s_mask,
                           bf16_t* __restrict__ smb, int n) {
    for (int i = blockIdx.x * blockDim.x + threadIdx.x; i < n; i += gridDim.x * blockDim.x)
        smb[i] = __float2bfloat16(hidden[i] * s_mask[i]);
}

// ---------- pre-pass: H/T = bf16(inp*h_mask) @ Wih/Wit^T + bias -> fp16 (R14-proven) ----------
__global__ __launch_bounds__(256) void k_ht(
    const float* __restrict__ inp, const float* __restrict__ h_mask,
    const bf16_t* __restrict__ Wihb, const float* __restrict__ bih,
    const bf16_t* __restrict__ Witb, const float* __restrict__ bitv,
    _Float16* __restrict__ ht)
{
    const int lane = threadIdx.x & 63;
    const int w    = threadIdx.x >> 6;
    const int r0   = blockIdx.y * 32 + (w >> 1) * 16;
    const int c0   = blockIdx.x * 64 + (w & 1) * 32;
    const int lr   = lane & 15;
    const int kg   = lane >> 4;

    f32x4 aH0 = {0,0,0,0}, aH1 = {0,0,0,0}, aT0 = {0,0,0,0}, aT1 = {0,0,0,0};
    const int R = r0 + lr;
    const float* ap = inp + (size_t)R * NHID + kg * 8;
    const float* mp = h_mask + (size_t)(R & 127) * NHID + kg * 8;
    const bf16_t* Bh = Wihb + (size_t)(c0 + lr) * NHID + kg * 8;
    const bf16_t* Bt = Witb + (size_t)(c0 + lr) * NHID + kg * 8;

    for (int k = 0; k < NHID; k += 32) {
        f32x4 x0 = *(const f32x4*)(ap + k), x1 = *(const f32x4*)(ap + k + 4);
        f32x4 m0 = *(const f32x4*)(mp + k), m1 = *(const f32x4*)(mp + k + 4);
        union { bf16_t h[8]; bf16x8 v; } af;
        #pragma unroll
        for (int q = 0; q < 4; ++q) {
            af.h[q]     = __float2bfloat16(x0[q] * m0[q]);
            af.h[q + 4] = __float2bfloat16(x1[q] * m1[q]);
        }
        bf16x8 bh0 = *(const bf16x8*)(Bh + k);
        bf16x8 bh1 = *(const bf16x8*)(Bh + (size_t)16 * NHID + k);
        bf16x8 bt0 = *(const bf16x8*)(Bt + k);
        bf16x8 bt1 = *(const bf16x8*)(Bt + (size_t)16 * NHID + k);
        aH0 = mfma16(af.v, bh0, aH0);
        aH1 = mfma16(af.v, bh1, aH1);
        aT0 = mfma16(af.v, bt0, aT0);
        aT1 = mfma16(af.v, bt1, aT1);
    }

    const int n0 = c0 + lr, n1 = n0 + 16;
    #pragma unroll
    for (int j = 0; j < 4; ++j) {
        const int R2 = r0 + kg * 4 + j;
        const int t = R2 >> 7, b = R2 & 127;
        _Float16* hrow = ht + ((size_t)(t * 2 + 0) * BATCH + b) * NHID;
        _Float16* trow = ht + ((size_t)(t * 2 + 1) * BATCH + b) * NHID;
        hrow[n0] = (_Float16)(aH0[j] + bih[n0]);
        hrow[n1] = (_Float16)(aH1[j] + bih[n1]);
        trow[n0] = (_Float16)(aT0[j] + bitv[n0]);
        trow[n1] = (_Float16)(aT1[j] + bitv[n1]);
    }
}

// batched 16B A loads: sc0 sc1; base pointer selects rotated 512B k-chunk-group
#define LDU(i, OFF, P) asm volatile("global_load_dwordx4 %0, %1, off offset:" OFF " sc0 sc1" \
                                    : "=v"(AR[i]) : "v"(P));
#define ISSUE8(M, s, P) \
    M(s+0,"0",P) M(s+1,"64",P) M(s+2,"128",P) M(s+3,"192",P) \
    M(s+4,"256",P) M(s+5,"320",P) M(s+6,"384",P) M(s+7,"448",P)
// MFMA must not hoist above the wait; ALU/SALU/DS may (0x1|0x2|0x4|0x80|0x100)
#define WAITV(N) do { asm volatile("s_waitcnt vmcnt(" #N ")" ::: "memory"); \
                      __builtin_amdgcn_sched_barrier(0x187); } while (0)
// B fragments from LDS, base RB = rotated 512B group of this row; XOR bank spread
#define CHUNK_R(c, RB) do { _Pragma("unroll") \
    for (int e = 0; e < 8; ++e) { \
        bf16x8 bf = *(const bf16x8*)((RB) + ((kg * 16 + e * 64) ^ xmask)); \
        acc = mfma16(as_bf16x8(AR[(c) * 8 + e]), bf, acc); } } while (0)

// 256 blocks x 256 threads (4 waves x 16 rows). Group g = bid>>7 owns rows [64g,64g+64);
// block-in-group gb owns cols [8gb,8gb+8): 16 gate-cols = full MFMA N-tile. LDS: all
// 5 layer pairs, 80 rows x 2048B = 160KB. R15 deltas vs R14 (de-correlate readers):
//  (1) row-stagger: wave w handles row-group (w+gb)&3  (pure wave permutation)
//  (2) k-rotation: A-loads/B-frags start at k-group (gb>>2)&3 (rotated 512B groups)
__global__ __launch_bounds__(256, 1) void k_rhn_persist(
    const float* __restrict__ hidden, const float* __restrict__ s_mask,
    const float* __restrict__ Wh,  const float* __restrict__ bh,
    const float* __restrict__ Wt,  const float* __restrict__ bt,
    const _Float16* __restrict__ ht,
    bf16_t* __restrict__ smbA, bf16_t* __restrict__ smbB,
    unsigned int* __restrict__ flags,   // [2][128] slots, 64B apart
    float* __restrict__ out)
{
    extern __shared__ char wlds[];      // 80 rows x 2048 B = 163840 B
    const int tid  = threadIdx.x;
    const int lane = tid & 63;
    const int wv   = tid >> 6;          // 0..3
    const int g    = blockIdx.x >> 7;
    const int gb   = blockIdx.x & (GRP_BLK - 1);
    const int c0   = gb * CPB;
    const int lr   = lane & 15;
    const int kg   = lane >> 4;
    const int wbase = g * 64 + ((wv + gb) & 3) * 16;   // row-staggered per block
    const int kp   = (gb >> 2) & 3;                    // k-rotation phase
    const int cc   = c0 + (lr & 7);
    const bool isT = lr >= 8;
    const int xmask = (lr & 7) << 4;

    // ---- stage ALL 5 recurrent pairs f32 -> bf16 LDS with 16B XOR placement ----
    for (int row = wv; row < 80; row += 4) {
        const int l = row >> 4, r = row & 15;
        const float* src = ((r < 8) ? Wh : Wt) + ((size_t)l * NHID + c0 + (r & 7)) * NHID;
        char* rb = wlds + (size_t)row * 2048;
        const int X = (r & 7) << 4;
        #pragma unroll
        for (int u = 0; u < 2; ++u) {
            union { bf16_t h[8]; u32x4 v; } pk;
            #pragma unroll
            for (int q = 0; q < 8; ++q)
                pk.h[q] = __float2bfloat16(src[lane * 16 + u * 8 + q]);
            *(u32x4*)(rb + ((lane * 32 + u * 16) ^ X)) = pk.v;
        }
    }

    // ---- per-lane state ----
    float biasl[NDEPTH];
    #pragma unroll
    for (int l = 0; l < NDEPTH; ++l)
        biasl[l] = isT ? bt[(size_t)l * NHID + cc] : bh[(size_t)l * NHID + cc];
    float sreg[4], smk[4];
    #pragma unroll
    for (int j = 0; j < 4; ++j) {
        const int row = wbase + kg * 4 + j;
        sreg[j] = hidden[(size_t)row * NHID + cc];
        smk[j]  = s_mask[(size_t)row * NHID + cc];
    }

    __syncthreads();   // LDS weights ready

    const size_t aoff = (size_t)(wbase + lr) * NHID + kg * 8;
    unsigned int rv = 0;
    int par = 0;

    for (int t = 0; t < SEQ; ++t) {
        #pragma unroll
        for (int l = 0; l < NDEPTH; ++l) {
            const bf16_t* Abuf = par ? smbB : smbA;
            bf16_t*       An   = par ? smbA : smbB;
            f32x4 acc = {0.f, 0.f, 0.f, 0.f};
            u32x4 AR[32];

            {   // recurrent GEMM, k-groups rotated by kp (A and B consistently)
                const bf16_t* aptr = Abuf + aoff;
                const char* rowb = wlds + (size_t)(l * 16 + lr) * 2048;
                const bf16_t* a0 = aptr + ((kp + 0) & 3) * 256;   // 256 bf16 = 512 B
                const bf16_t* a1 = aptr + ((kp + 1) & 3) * 256;
                const bf16_t* a2 = aptr + ((kp + 2) & 3) * 256;
                const bf16_t* a3 = aptr + ((kp + 3) & 3) * 256;
                const char* rb0 = rowb + ((kp + 0) & 3) * 512;
                const char* rb1 = rowb + ((kp + 1) & 3) * 512;
                const char* rb2 = rowb + ((kp + 2) & 3) * 512;
                const char* rb3 = rowb + ((kp + 3) & 3) * 512;
                ISSUE8(LDU, 0,  a0)
                ISSUE8(LDU, 8,  a1)
                ISSUE8(LDU, 16, a2)
                ISSUE8(LDU, 24, a3)
                WAITV(24); CHUNK_R(0, rb0);
                WAITV(16); CHUNK_R(1, rb1);
                WAITV(8);  CHUNK_R(2, rb2);
                WAITV(0);  CHUNK_R(3, rb3);
            }
            if (l == 0) {   // add precomputed input contribution (fp16, plain loads)
                const _Float16* hp = ht + (size_t)(t * 2 + (isT ? 1 : 0)) * PANEL + cc;
                #pragma unroll
                for (int j = 0; j < 4; ++j)
                    acc[j] += (float)hp[(size_t)(wbase + kg * 4 + j) * NHID];
            }

            // ---- epilogue: C col = lane&15 (gate-col), row = kg*4 + j ----
            const float vb = biasl[l];
            #pragma unroll
            for (int j = 0; j < 4; ++j) {
                float v = acc[j] + vb;
                float o = swzf<0x201F>(v);            // lane^8: H-pre <-> T-pre
                float Hv = tanhf(v);
                float Tv = 1.f / (1.f + __expf(-o));
                float sv = sreg[j];
                float sn = (Hv - sv) * Tv + sv;       // valid on H-lanes (lr<8)
                sreg[j] = sn;
                const int row = wbase + kg * 4 + j;

                // pack 8 cols x bf16 (lanes lr=0..7) into 16B on lane lr==0
                uint32_t a  = (uint32_t)f32_to_bf16_bits(sn * smk[j]);
                uint32_t b1 = swzu<0x041F>(a);                     // lane^1
                uint32_t w  = (a & 0xffffu) | (b1 << 16);
                uint32_t c2 = swzu<0x081F>(w);                     // lane^2
                uint32_t e1 = swzu<0x101F>(w);                     // lane^4
                uint32_t e2 = swzu<0x101F>(c2);
                if (lr == 0) {
                    uint64_t q0 = (uint64_t)w  | ((uint64_t)c2 << 32);
                    uint64_t q1 = (uint64_t)e1 | ((uint64_t)e2 << 32);
                    uint64_t* p = (uint64_t*)(An + (size_t)row * NHID + c0);
                    __hip_atomic_store(p,     q0, __ATOMIC_RELAXED, __HIP_MEMORY_SCOPE_AGENT);
                    __hip_atomic_store(p + 1, q1, __ATOMIC_RELAXED, __HIP_MEMORY_SCOPE_AGENT);
                }
                if (l == NDEPTH - 1 && lr < 8) {      // out: plain cached stores
                    out[((size_t)t * BATCH + row) * NHID + cc] = sn;
                    if (t == SEQ - 1)
                        out[(size_t)SEQ * BATCH * NHID + (size_t)row * NHID + cc] = sn;
                }
            }

            // ---- group-scoped flat all-to-all barrier (R11-proven protocol) ----
            ++rv;
            if (!(t == SEQ - 1 && l == NDEPTH - 1)) {
                __syncthreads();   // drains vmcnt: block's state stores acked
                if (tid == 0)
                    __hip_atomic_store(&flags[(g * GRP_BLK + gb) * 16], rv,
                                       __ATOMIC_RELAXED, __HIP_MEMORY_SCOPE_AGENT);
                if (tid < 64) {    // wave 0 polls the group's 128 flags: 2 loads/lane
                    const unsigned int* p0 = &flags[(g * GRP_BLK + lane) * 16];
                    const unsigned int* p1 = &flags[(g * GRP_BLK + 64 + lane) * 16];
                    for (;;) {
                        unsigned int f0 = __hip_atomic_load(p0, __ATOMIC_RELAXED,
                                                            __HIP_MEMORY_SCOPE_AGENT);
                        unsigned int f1 = __hip_atomic_load(p1, __ATOMIC_RELAXED,
                                                            __HIP_MEMORY_SCOPE_AGENT);
                        if (__all(f0 >= rv && f1 >= rv)) break;
                        __builtin_amdgcn_s_sleep(2);
                    }
                }
                __syncthreads();   // release other waves
            }
            par ^= 1;
        }
    }
}

extern "C" void kernel_launch(void* const* d_in, const int* in_sizes, int n_in,
                              void* d_out, int out_size, void* d_ws, size_t ws_size,
                              hipStream_t stream) {
    (void)in_sizes; (void)n_in; (void)out_size; (void)ws_size;

    const float* inp    = (const float*)d_in[0];
    const float* hidden = (const float*)d_in[1];
    const float* h_mask = (const float*)d_in[2];
    const float* s_mask = (const float*)d_in[3];
    const float* Wih    = (const float*)d_in[4];
    const float* bih    = (const float*)d_in[5];
    const float* Wit    = (const float*)d_in[6];
    const float* bitv   = (const float*)d_in[7];
    const float* Wh     = (const float*)d_in[8];
    const float* bh     = (const float*)d_in[9];
    const float* Wt     = (const float*)d_in[10];
    const float* bt     = (const float*)d_in[11];
    float* out = (float*)d_out;

    // ws: ht fp16 [S][2][B][HID] 104.9MB | Wihb 2MB | Witb 2MB | smbA | smbB | flags
    _Float16* ht   = (_Float16*)d_ws;
    bf16_t* Wihb   = (bf16_t*)(ht + (size_t)SEQ * 2 * PANEL);
    bf16_t* Witb   = Wihb + (size_t)NHID * NHID;
    bf16_t* smbA   = Witb + (size_t)NHID * NHID;
    bf16_t* smbB   = smbA + PANEL;
    unsigned int* flags = (unsigned int*)(smbB + PANEL);

    hipMemsetAsync(flags, 0, NBLK * 16 * sizeof(unsigned int), stream);
    k_cast_bf16<<<dim3(512), dim3(256), 0, stream>>>(Wih, Wihb, NHID * NHID);
    k_cast_bf16<<<dim3(512), dim3(256), 0, stream>>>(Wit, Witb, NHID * NHID);
    k_init_smb<<<dim3(64), dim3(256), 0, stream>>>(hidden, s_mask, smbA, BATCH * NHID);
    k_ht<<<dim3(NHID / 64, SB / 32), dim3(256), 0, stream>>>(
        inp, h_mask, Wihb, bih, Witb, bitv, ht);

    const size_t ldsBytes = (size_t)80 * 2048;   // 160 KB exactly
    hipFuncSetAttribute((const void*)k_rhn_persist,
                        hipFuncAttributeMaxDynamicSharedMemorySize, (int)ldsBytes);
    k_rhn_persist<<<dim3(NBLK), dim3(256), ldsBytes, stream>>>(
        hidden, s_mask, Wh, bh, Wt, bt, ht, smbA, smbB, flags, out);
}